// Round 1
// baseline (177.678 us; speedup 1.0000x reference)
//
#include <hip/hip_runtime.h>
#include <stdint.h>

// Match numpy semantics: no FMA contraction anywhere in decision-critical math.
#pragma clang fp contract(off)

#define N_ANCHORS 172032  // compile-time problem constant
#define MAX_OUT 200
#define BLK 1024
#define GRID 168          // GRID*BLK == N_ANCHORS exactly
#define NW (BLK / 64)
#define SEG 32            // per-block segment capacity (lambda~9.6, P(>32)~1e-9; guarded)
#define NKEY (GRID * SEG) // 5376 — compact-key capacity (no csel<=2048 guard needed anymore)
#define RMAX 1024         // suppression-matrix rank capacity; rank_200 < 900 (round-5
                          // evidence) so picks live in ranks [0,1024). Guarded by ln<200
                          // fallback: if the 200th pick would need rank>=RMAX the scan
                          // exhausts alive and we fall back to the exact path.
#define MASKW (RMAX / 64) // 16 ull words per row
#define MBLK 256          // k_mask block size
#define MROWS 16          // rows per k_mask block
#define VT 2.35f          // fixed prefix threshold: scores ~ N(0,1) =>
                          // csel ~ 1615 +/- 40; rank_200 < 900 (round-5 evidence).
                          // Inline exact fallback guards all.

typedef unsigned long long ull;
static_assert(GRID * BLK == N_ANCHORS, "grid covers anchors exactly");
static_assert(RMAX % 64 == 0, "mask words");

// f64 decode: f32 inputs upcast to f64, reference op order. Returns (y1,x1,y2,x2).
__device__ __forceinline__ void decode_box_d(const float4* __restrict__ reg,
                                             const float4* __restrict__ anc, int i,
                                             double b[4]) {
#pragma clang fp contract(off)
    float4 r = reg[i];
    float4 a = anc[i];
    double dx = (double)r.x * 0.1;
    double dy = (double)r.y * 0.1;
    double dw = (double)r.z * 0.2;
    double dh = (double)r.w * 0.2;
    double xa = (double)a.x, ya = (double)a.y, wa = (double)a.z, ha = (double)a.w;
    double xc = dx * wa; xc = xc + xa;     // dx*w_a + x_a
    double yc = dy * ha; yc = yc + ya;     // dy*h_a + y_a
    double w = exp(dw) * wa;
    double h = exp(dh) * ha;
    double h2 = h * 0.5, w2 = w * 0.5;
    b[0] = yc - h2; b[1] = xc - w2; b[2] = yc + h2; b[3] = xc + w2;
}

// Gather + f64 decode one output row (boxes + landmarks), write f32.
__device__ __forceinline__ void write_row(const float4* __restrict__ reg,
                                          const float4* __restrict__ anc,
                                          const float* __restrict__ lnd,
                                          int q, int idx, float* __restrict__ out) {
#pragma clang fp contract(off)
    float b[4] = {0.f, 0.f, 0.f, 0.f};
    float l10[10] = {0.f, 0.f, 0.f, 0.f, 0.f, 0.f, 0.f, 0.f, 0.f, 0.f};
    if (idx >= 0) {
        double bb[4];
        decode_box_d(reg, anc, idx, bb);
        b[0] = (float)bb[0]; b[1] = (float)bb[1]; b[2] = (float)bb[2]; b[3] = (float)bb[3];
        float4 a = anc[idx];
        double xa = (double)a.x, ya = (double)a.y, wa = (double)a.z, ha = (double)a.w;
        for (int j = 0; j < 5; ++j) {
            double lx = (double)lnd[idx * 10 + 2 * j]     * 0.1;
            double ly = (double)lnd[idx * 10 + 2 * j + 1] * 0.1;
            lx = lx * wa; lx = lx + xa;
            ly = ly * ha; ly = ly + ya;
            l10[2 * j] = (float)lx; l10[2 * j + 1] = (float)ly;
        }
    }
    for (int c = 0; c < 4; ++c)  out[q * 4 + c] = b[c];
    for (int c = 0; c < 10; ++c) out[MAX_OUT * 4 + q * 10 + c] = l10[c];
}

__device__ __forceinline__ ull wmax(ull k) {
    for (int d = 32; d > 0; d >>= 1) {
        ull o = __shfl_down(k, d, 64);
        if (o > k) k = o;
    }
    return k;
}

// f64 IoU > 0.4 test, reference op order (validated in prior rounds).
__device__ __forceinline__ bool iou_gt_f4(float4 a, float4 p) {
#pragma clang fp contract(off)
    double y1 = (double)a.x, x1 = (double)a.y, y2 = (double)a.z, x2 = (double)a.w;
    double p0 = (double)p.x, p1 = (double)p.y, p2 = (double)p.z, p3 = (double)p.w;
    double ih = fmin(y2, p2) - fmax(y1, p0); ih = fmax(ih, 0.0);
    double iw = fmin(x2, p3) - fmax(x1, p1); iw = fmax(iw, 0.0);
    double inter = ih * iw;
    double aj = (y2 - y1) * (x2 - x1);
    double ap = (p2 - p0) * (p3 - p1);
    double den = aj + ap; den = den - inter; den = den + 1e-12;
    return (inter / den) > 0.4;
}

// ---------- kernel 1: segment compaction (no atomics, no memset needed) ----------
__global__ void __launch_bounds__(BLK) k_seg(const float2* __restrict__ cls,
                                             int* __restrict__ segcnt,
                                             ull* __restrict__ segkeys) {
    __shared__ int wcnt[NW];
    int tid = threadIdx.x, bid = blockIdx.x;
    int i = bid * BLK + tid;
    float sc = cls[i].y;                   // score = cls[:,1]
    bool c = (sc > VT);
    ull key = 0ull;
    if (c) key = ((ull)__float_as_uint(sc) << 32)
               | (ull)(0xFFFFFFFFu - (unsigned int)i);
    ull m = __ballot(c);
    int wid = tid >> 6, lane = tid & 63;
    if (lane == 0) wcnt[wid] = __popcll(m);
    __syncthreads();
    if (tid == 0) {
        int s = 0;
        for (int w = 0; w < NW; ++w) { int t = wcnt[w]; wcnt[w] = s; s += t; }
        segcnt[bid] = s;                   // unconditional (overflow detected downstream)
    }
    __syncthreads();
    if (c) {
        int pos = wcnt[wid] + __popcll(m & ((1ull << lane) - 1ull));
        if (pos < SEG) segkeys[bid * SEG + pos] = key;
    }
}

// emit one ranked candidate: idx + decoded box in rank order
__device__ __forceinline__ void rank_emit(const float4* __restrict__ reg,
                                          const float4* __restrict__ anc,
                                          int rank, ull key,
                                          int* __restrict__ gidx,
                                          float4* __restrict__ gbox) {
    int idx = (int)(0xFFFFFFFFu - (unsigned int)key);
    gidx[rank] = idx;
    double b[4];
    decode_box_d(reg, anc, idx, b);
    gbox[rank] = make_float4((float)b[0], (float)b[1], (float)b[2], (float)b[3]);
}

// ---------- kernel 2: barrier-free rank-counting sort (replaces 66-pass bitonic) ----------
// Each candidate's rank = #keys strictly greater (keys unique: score bits desc, idx asc).
// Scatters decoded boxes + indices into rank order for ranks < RMAX.
__global__ void __launch_bounds__(BLK) k_rank(const float4* __restrict__ reg,
                                              const float4* __restrict__ anc,
                                              const int* __restrict__ segcnt,
                                              const ull* __restrict__ segkeys,
                                              int* __restrict__ meta,
                                              int* __restrict__ gidx,
                                              float4* __restrict__ gbox) {
    __shared__ ull skeys[NKEY];            // 43 KB
    __shared__ int scnt[GRID], spre[GRID];
    __shared__ int s_ok, s_csel;
    int tid = threadIdx.x;
    for (int s = tid; s < GRID; s += BLK) scnt[s] = segcnt[s];
    __syncthreads();
    if (tid == 0) {
        int acc = 0, ok = 1;
        for (int s = 0; s < GRID; ++s) {
            spre[s] = acc;
            if (scnt[s] > SEG) ok = 0;     // segment overflow -> exact fallback in k_pick
            acc += scnt[s];
        }
        s_ok = ok; s_csel = acc;
        meta[0] = ok; meta[1] = acc;
    }
    __syncthreads();
    if (s_ok == 0) return;                 // uniform
    int csel = s_csel;                     // <= NKEY guaranteed by per-seg cap

    // gather compact keys
    for (int t = tid; t < GRID * SEG; t += BLK) {
        int s = t / SEG, k = t % SEG;
        if (k < scnt[s]) skeys[spre[s] + k] = segkeys[s * SEG + k];
    }
    // zero-fill unranked slots (k_mask reads gbox[0..RMAX))
    for (int r = csel + tid; r < RMAX; r += BLK) {
        gidx[r] = -1;
        gbox[r] = make_float4(0.f, 0.f, 0.f, 0.f);
    }
    __syncthreads();

    if (csel <= 2 * BLK) {                 // common case (csel ~1615): 2 slots/thread, one j-loop
        ull k0 = (tid < csel) ? skeys[tid] : 0ull;
        ull k1 = (BLK + tid < csel) ? skeys[BLK + tid] : 0ull;
        int r0 = 0, r1 = 0;
#pragma unroll 4
        for (int j = 0; j < csel; ++j) {
            ull kj = skeys[j];             // broadcast LDS read (all lanes same addr)
            r0 += (kj > k0);
            r1 += (kj > k1);
        }
        if (tid < csel && r0 < RMAX)       rank_emit(reg, anc, r0, k0, gidx, gbox);
        if (BLK + tid < csel && r1 < RMAX) rank_emit(reg, anc, r1, k1, gidx, gbox);
    } else {                               // rare large-csel path (still exact)
        for (int c = tid; c < csel; c += BLK) {
            ull kc = skeys[c];
            int rk = 0;
            for (int j = 0; j < csel; ++j) rk += (skeys[j] > kc);
            if (rk < RMAX) rank_emit(reg, anc, rk, kc, gidx, gbox);
        }
    }
}

// ---------- kernel 3: parallel pairwise suppression bitmatrix (64 CUs) ----------
// gmask[r][w] bit e set <=> iou(box[w*64+e], box[r]) > 0.4 (f64, reference op order).
// Diagonal bit is naturally set (iou(b,b)~1) => pick removes itself, matching the
// reference's self-suppression semantics (incl. degenerate zero-area repeat picks).
__global__ void __launch_bounds__(MBLK) k_mask(const int* __restrict__ meta,
                                               const float4* __restrict__ gbox,
                                               ull* __restrict__ gmask) {
    __shared__ float4 cbox[RMAX];          // 16 KB
    if (meta[0] == 0) return;              // uniform (before any barrier)
    int csel = meta[1];
    int rlim = csel < RMAX ? csel : RMAX;
    int tid = threadIdx.x;
    for (int t = tid; t < RMAX; t += MBLK) cbox[t] = gbox[t];
    __syncthreads();
    int row  = blockIdx.x * MROWS + (tid & (MROWS - 1)); // 16-lane groups share a word
    int word = tid >> 4;                                  // => broadcast LDS col reads
    if (row >= rlim) return;
    float4 br = cbox[row];
    ull bits = 0ull;
    int cbase = word << 6;
#pragma unroll 4
    for (int e = 0; e < 64; ++e) {
        int c = cbase + e;
        if (c < rlim && iou_gt_f4(cbox[c], br)) bits |= (1ull << e);
    }
    gmask[row * MASKW + word] = bits;
}

// ---------- kernel 4: serial bit-scan greedy + output (+inline exact fallback) ----------
__global__ void __launch_bounds__(BLK) k_pick(const float2* __restrict__ cls,
                                              const float4* __restrict__ reg,
                                              const float4* __restrict__ anc,
                                              const float* __restrict__ lnd,
                                              const int* __restrict__ meta,
                                              const int* __restrict__ gidx,
                                              const ull* __restrict__ gmask,
                                              float* __restrict__ sbuf,
                                              float* __restrict__ out) {
    __shared__ ull smask[RMAX * MASKW];    // 128 KB (gfx950: 160 KiB/WG available)
    __shared__ int s_kept[MAX_OUT];
    __shared__ int s_ln;
    __shared__ ull warr[NW];               // fallback
    __shared__ ull s_win;
    __shared__ double s_pb[5];

    int tid = threadIdx.x;
    bool pre_ok = (meta[0] != 0);
    int csel = meta[1];
    int ln = 0;

    if (pre_ok) {
        int rlim = csel < RMAX ? csel : RMAX;
        int nwords = rlim * MASKW;
        for (int t = tid; t < nwords; t += BLK) smask[t] = gmask[t];
        __syncthreads();
        // single-wave greedy scan: lanes 0..15 own 64-rank alive words
        if (tid < 64) {
            int lane = tid;
            ull alive = 0ull;
            if (lane < MASKW) {
                int lo = lane << 6;
                int n = rlim - lo;
                if (n >= 64) alive = ~0ull;
                else if (n > 0) alive = (1ull << n) - 1ull;
            }
            int lnl = 0;
            while (lnl < MAX_OUT) {
                ull bal = __ballot(alive != 0ull);
                if (bal == 0ull) break;                       // exhausted -> fallback
                int wl = __ffsll(bal) - 1;                    // lowest nonzero word
                int myb = alive ? (__ffsll(alive) - 1) : 0;
                int bit = __shfl(myb, wl, 64);
                int p = (wl << 6) + bit;                      // pick = first alive rank
                if (lane == 0) s_kept[lnl] = p;               // store RANK
                lnl++;
                ull rw = (lane < MASKW) ? smask[p * MASKW + lane] : 0ull;
                alive &= ~rw;                                 // row-AND (self-bit in row)
            }
            if (lane == 0) s_ln = lnl;
        }
        __syncthreads();
        ln = s_ln;
    }

    bool need = (!pre_ok) || (ln < MAX_OUT);                  // uniform
    if (!need) {
        if (tid < MAX_OUT) write_row(reg, anc, lnd, tid, gidx[s_kept[tid]], out);
        return;
    }

    // ---- inline exact fallback: literal greedy over all N (round-10 validated) ----
    for (int i = tid; i < N_ANCHORS; i += BLK) {
        float sc = cls[i].y;
        sbuf[i] = ((double)sc > 0.4) ? sc : 0.0f;
    }
    __syncthreads();
    ln = 0;
    for (int oi = 0; oi < MAX_OUT; ++oi) {
        ull k = 0;
        for (int i = tid; i < N_ANCHORS; i += BLK) {
            ull kk = ((ull)__float_as_uint(sbuf[i]) << 32)
                   | (ull)(0xFFFFFFFFu - (unsigned int)i);
            if (kk > k) k = kk;
        }
        k = wmax(k);
        if ((tid & 63) == 0) warr[tid >> 6] = k;
        __syncthreads();
        if (tid < 64) {
            ull v = (tid < NW) ? warr[tid] : 0ull;
            v = wmax(v);
            if (tid == 0) s_win = v;
        }
        __syncthreads();
        ull win = s_win;
        if ((win >> 32) == 0u) break;
        int pidx = (int)(0xFFFFFFFFu - (unsigned int)win);
        if (tid == 0) {
            double b[4];
            decode_box_d(reg, anc, pidx, b);
            s_pb[0] = b[0]; s_pb[1] = b[1]; s_pb[2] = b[2]; s_pb[3] = b[3];
            s_pb[4] = (b[2] - b[0]) * (b[3] - b[1]);
            s_kept[oi] = pidx;                                // store IDX (fallback)
        }
        __syncthreads();
        double p0 = s_pb[0], p1 = s_pb[1], p2 = s_pb[2], p3 = s_pb[3], pa = s_pb[4];
        for (int i = tid; i < N_ANCHORS; i += BLK) {
            float v = sbuf[i];
            if (v != 0.0f) {
                double b[4];
                decode_box_d(reg, anc, i, b);
                double ih = fmin(b[2], p2) - fmax(b[0], p0); ih = fmax(ih, 0.0);
                double iw = fmin(b[3], p3) - fmax(b[1], p1); iw = fmax(iw, 0.0);
                double inter = ih * iw;
                double aa = (b[2] - b[0]) * (b[3] - b[1]);
                double den = aa + pa; den = den - inter; den = den + 1e-12;
                if (inter / den > 0.4) sbuf[i] = 0.0f;  // kills the pick too
            }
        }
        __syncthreads();
        ln = oi + 1;
    }
    __syncthreads();
    if (tid < MAX_OUT)
        write_row(reg, anc, lnd, tid, (tid < ln) ? s_kept[tid] : -1, out);
}

extern "C" void kernel_launch(void* const* d_in, const int* in_sizes, int n_in,
                              void* d_out, int out_size, void* d_ws, size_t ws_size,
                              hipStream_t stream) {
    const float2* cls = (const float2*)d_in[0];    // (N,2) f32
    const float4* reg = (const float4*)d_in[1];    // (N,4) f32
    const float*  lnd = (const float*)d_in[2];     // (N,10) f32
    const float4* anc = (const float4*)d_in[3];    // (N,4) f32

    uint8_t* w = (uint8_t*)d_ws;
    int*    segcnt  = (int*)w;                  //      0: 672 B
    int*    meta    = (int*)(w + 768);          //    768: {ok, csel}
    ull*    segkeys = (ull*)(w + 1024);         //   1024: 168*32*8 = 43008 B
    // main-path scratch unions with fallback-only sbuf (total ws use: 732160 B, unchanged)
    int*    gidx    = (int*)(w + 44032);        //  44032: 1024*4  = 4096 B
    float4* gbox    = (float4*)(w + 48128);     //  48128: 1024*16 = 16384 B
    ull*    gmask   = (ull*)(w + 64512);        //  64512: 1024*16*8 = 131072 B
    float*  sbuf    = (float*)(w + 44032);      //  44032: N*4 B (fallback only, aliases above)

    k_seg <<<GRID, BLK, 0, stream>>>(cls, segcnt, segkeys);
    k_rank<<<1, BLK, 0, stream>>>(reg, anc, segcnt, segkeys, meta, gidx, gbox);
    k_mask<<<RMAX / MROWS, MBLK, 0, stream>>>(meta, gbox, gmask);
    k_pick<<<1, BLK, 0, stream>>>(cls, reg, anc, lnd, meta, gidx, gmask, sbuf,
                                  (float*)d_out);
}

// Round 2
// 150.115 us; speedup vs baseline: 1.1836x; 1.1836x over previous
//
#include <hip/hip_runtime.h>
#include <stdint.h>

// Match numpy semantics: no FMA contraction anywhere in decision-critical math.
#pragma clang fp contract(off)

#define N_ANCHORS 172032  // compile-time problem constant
#define MAX_OUT 200
#define BLK 1024
#define GRID 168          // GRID*BLK == N_ANCHORS exactly
#define NW (BLK / 64)
#define SEG 32            // per-block segment capacity (lambda~9.6, P(>32)~1e-9; guarded)
#define NKEY (GRID * SEG) // 5376 — compact-key capacity
#define RMAX 1024         // suppression-matrix rank capacity; rank_200 < 900 (round-5
                          // evidence) so picks live in ranks [0,1024). Guarded by ln<200
                          // fallback: if the 200th pick would need rank>=RMAX the scan
                          // exhausts alive and we fall back to the exact path.
#define MASKW (RMAX / 64) // 16 ull words per row
#define MBLK 256          // k_mask block size
#define MROWS 16          // rows per k_mask block
#define RCAND 64          // candidates ranked per k_rank block (one wave)
#define RGRID (NKEY / RCAND) // 84 rank blocks (only ~csel/64 ~ 26 stay active)
#define RBLK 256          // k_rank block size (staging width; count uses wave 0)
#define VT 2.35f          // fixed prefix threshold: scores ~ N(0,1) =>
                          // csel ~ 1615 +/- 40; rank_200 < 900 (round-5 evidence).
                          // Inline exact fallback guards all.

typedef unsigned long long ull;
static_assert(GRID * BLK == N_ANCHORS, "grid covers anchors exactly");
static_assert(RMAX % 64 == 0, "mask words");
static_assert(RGRID * RCAND == NKEY, "rank grid covers key capacity");

// f64 decode: f32 inputs upcast to f64, reference op order. Returns (y1,x1,y2,x2).
__device__ __forceinline__ void decode_box_d(const float4* __restrict__ reg,
                                             const float4* __restrict__ anc, int i,
                                             double b[4]) {
#pragma clang fp contract(off)
    float4 r = reg[i];
    float4 a = anc[i];
    double dx = (double)r.x * 0.1;
    double dy = (double)r.y * 0.1;
    double dw = (double)r.z * 0.2;
    double dh = (double)r.w * 0.2;
    double xa = (double)a.x, ya = (double)a.y, wa = (double)a.z, ha = (double)a.w;
    double xc = dx * wa; xc = xc + xa;     // dx*w_a + x_a
    double yc = dy * ha; yc = yc + ya;     // dy*h_a + y_a
    double w = exp(dw) * wa;
    double h = exp(dh) * ha;
    double h2 = h * 0.5, w2 = w * 0.5;
    b[0] = yc - h2; b[1] = xc - w2; b[2] = yc + h2; b[3] = xc + w2;
}

// Gather + f64 decode one output row (boxes + landmarks), write f32.
__device__ __forceinline__ void write_row(const float4* __restrict__ reg,
                                          const float4* __restrict__ anc,
                                          const float* __restrict__ lnd,
                                          int q, int idx, float* __restrict__ out) {
#pragma clang fp contract(off)
    float b[4] = {0.f, 0.f, 0.f, 0.f};
    float l10[10] = {0.f, 0.f, 0.f, 0.f, 0.f, 0.f, 0.f, 0.f, 0.f, 0.f};
    if (idx >= 0) {
        double bb[4];
        decode_box_d(reg, anc, idx, bb);
        b[0] = (float)bb[0]; b[1] = (float)bb[1]; b[2] = (float)bb[2]; b[3] = (float)bb[3];
        float4 a = anc[idx];
        double xa = (double)a.x, ya = (double)a.y, wa = (double)a.z, ha = (double)a.w;
        for (int j = 0; j < 5; ++j) {
            double lx = (double)lnd[idx * 10 + 2 * j]     * 0.1;
            double ly = (double)lnd[idx * 10 + 2 * j + 1] * 0.1;
            lx = lx * wa; lx = lx + xa;
            ly = ly * ha; ly = ly + ya;
            l10[2 * j] = (float)lx; l10[2 * j + 1] = (float)ly;
        }
    }
    for (int c = 0; c < 4; ++c)  out[q * 4 + c] = b[c];
    for (int c = 0; c < 10; ++c) out[MAX_OUT * 4 + q * 10 + c] = l10[c];
}

__device__ __forceinline__ ull wmax(ull k) {
    for (int d = 32; d > 0; d >>= 1) {
        ull o = __shfl_down(k, d, 64);
        if (o > k) k = o;
    }
    return k;
}

// f64 IoU > 0.4 test, reference op order (validated in prior rounds).
__device__ __forceinline__ bool iou_gt_f4(float4 a, float4 p) {
#pragma clang fp contract(off)
    double y1 = (double)a.x, x1 = (double)a.y, y2 = (double)a.z, x2 = (double)a.w;
    double p0 = (double)p.x, p1 = (double)p.y, p2 = (double)p.z, p3 = (double)p.w;
    double ih = fmin(y2, p2) - fmax(y1, p0); ih = fmax(ih, 0.0);
    double iw = fmin(x2, p3) - fmax(x1, p1); iw = fmax(iw, 0.0);
    double inter = ih * iw;
    double aj = (y2 - y1) * (x2 - x1);
    double ap = (p2 - p0) * (p3 - p1);
    double den = aj + ap; den = den - inter; den = den + 1e-12;
    return (inter / den) > 0.4;
}

// ---------- kernel 1: segment compaction (no atomics, no memset needed) ----------
__global__ void __launch_bounds__(BLK) k_seg(const float2* __restrict__ cls,
                                             int* __restrict__ segcnt,
                                             ull* __restrict__ segkeys) {
    __shared__ int wcnt[NW];
    int tid = threadIdx.x, bid = blockIdx.x;
    int i = bid * BLK + tid;
    float sc = cls[i].y;                   // score = cls[:,1]
    bool c = (sc > VT);
    ull key = 0ull;
    if (c) key = ((ull)__float_as_uint(sc) << 32)
               | (ull)(0xFFFFFFFFu - (unsigned int)i);
    ull m = __ballot(c);
    int wid = tid >> 6, lane = tid & 63;
    if (lane == 0) wcnt[wid] = __popcll(m);
    __syncthreads();
    if (tid == 0) {
        int s = 0;
        for (int w = 0; w < NW; ++w) { int t = wcnt[w]; wcnt[w] = s; s += t; }
        segcnt[bid] = s;                   // unconditional (overflow detected downstream)
    }
    __syncthreads();
    if (c) {
        int pos = wcnt[wid] + __popcll(m & ((1ull << lane) - 1ull));
        if (pos < SEG) segkeys[bid * SEG + pos] = key;
    }
}

// emit one ranked candidate: idx + decoded box in rank order
__device__ __forceinline__ void rank_emit(const float4* __restrict__ reg,
                                          const float4* __restrict__ anc,
                                          int rank, ull key,
                                          int* __restrict__ gidx,
                                          float4* __restrict__ gbox) {
    int idx = (int)(0xFFFFFFFFu - (unsigned int)key);
    gidx[rank] = idx;
    double b[4];
    decode_box_d(reg, anc, idx, b);
    gbox[rank] = make_float4((float)b[0], (float)b[1], (float)b[2], (float)b[3]);
}

// ---------- kernel 2: PARALLEL rank-counting sort (84 blocks, ~26 active CUs) ----------
// Each block redundantly computes the segment prefix, stages the dense keys into its
// own LDS, then ONE WAVE ranks RCAND=64 candidates: rank = #keys strictly greater
// (keys unique: score bits desc, idx asc). One wave per CU avoids 4-way LDS-pipe
// serialization of the broadcast reads. Value-based ranks => block order irrelevant.
__global__ void __launch_bounds__(RBLK) k_rank(const float4* __restrict__ reg,
                                               const float4* __restrict__ anc,
                                               const int* __restrict__ segcnt,
                                               const ull* __restrict__ segkeys,
                                               int* __restrict__ meta,
                                               int* __restrict__ gidx,
                                               float4* __restrict__ gbox) {
    __shared__ ull skeys[NKEY];            // 43 KB
    __shared__ int scnt[GRID], spre[GRID];
    __shared__ int s_ok, s_csel;
    int tid = threadIdx.x;
    for (int s = tid; s < GRID; s += RBLK) scnt[s] = segcnt[s];
    __syncthreads();
    if (tid == 0) {
        int acc = 0, ok = 1;
        for (int s = 0; s < GRID; ++s) {
            spre[s] = acc;
            if (scnt[s] > SEG) ok = 0;     // segment overflow -> exact fallback in k_pick
            acc += scnt[s];
        }
        s_ok = ok; s_csel = acc;
        if (blockIdx.x == 0) { meta[0] = ok; meta[1] = acc; }
    }
    __syncthreads();
    if (s_ok == 0) return;                 // uniform
    int csel = s_csel;                     // <= NKEY guaranteed by per-seg cap
    int cbase = blockIdx.x * RCAND;
    if (cbase >= csel) return;             // inactive tail blocks exit early (uniform)

    // stage dense keys (predicated scatter from padded segkeys; 21 iters)
    for (int t = tid; t < GRID * SEG; t += RBLK) {
        int s = t >> 5, k = t & (SEG - 1);
        if (k < scnt[s]) skeys[spre[s] + k] = segkeys[t];
    }
    __syncthreads();

    // one wave: broadcast-count ranks for this block's 64 candidates
    if (tid < RCAND) {
        int c = cbase + tid;
        if (c < csel) {
            ull kc = skeys[c];
            int rk = 0;
#pragma unroll 4
            for (int j = 0; j < csel; ++j)
                rk += (skeys[j] > kc) ? 1 : 0;   // broadcast LDS read (uniform addr)
            if (rk < RMAX) rank_emit(reg, anc, rk, kc, gidx, gbox);
        }
    }
}

// ---------- kernel 3: parallel pairwise suppression bitmatrix (64 CUs) ----------
// gmask[r][w] bit e set <=> iou(box[w*64+e], box[r]) > 0.4 (f64, reference op order).
// Diagonal bit is naturally set (iou(b,b)~1) => pick removes itself, matching the
// reference's self-suppression semantics (incl. degenerate zero-area repeat picks).
__global__ void __launch_bounds__(MBLK) k_mask(const int* __restrict__ meta,
                                               const float4* __restrict__ gbox,
                                               ull* __restrict__ gmask) {
    __shared__ float4 cbox[RMAX];          // 16 KB
    if (meta[0] == 0) return;              // uniform (before any barrier)
    int csel = meta[1];
    int rlim = csel < RMAX ? csel : RMAX;
    int tid = threadIdx.x;
    for (int t = tid; t < RMAX; t += MBLK) cbox[t] = gbox[t];  // >=rlim slots unused
    __syncthreads();
    int row  = blockIdx.x * MROWS + (tid & (MROWS - 1)); // 16-lane groups share a word
    int word = tid >> 4;                                  // => broadcast LDS col reads
    if (row >= rlim) return;
    float4 br = cbox[row];
    ull bits = 0ull;
    int cbase = word << 6;
#pragma unroll 4
    for (int e = 0; e < 64; ++e) {
        int c = cbase + e;
        if (c < rlim && iou_gt_f4(cbox[c], br)) bits |= (1ull << e);
    }
    gmask[row * MASKW + word] = bits;
}

// ---------- kernel 4: serial bit-scan greedy + output (+inline exact fallback) ----------
__global__ void __launch_bounds__(BLK) k_pick(const float2* __restrict__ cls,
                                              const float4* __restrict__ reg,
                                              const float4* __restrict__ anc,
                                              const float* __restrict__ lnd,
                                              const int* __restrict__ meta,
                                              const int* __restrict__ gidx,
                                              const ull* __restrict__ gmask,
                                              float* __restrict__ sbuf,
                                              float* __restrict__ out) {
    __shared__ ull smask[RMAX * MASKW];    // 128 KB (gfx950: 160 KiB/WG available)
    __shared__ int s_kept[MAX_OUT];
    __shared__ int s_ln;
    __shared__ ull warr[NW];               // fallback
    __shared__ ull s_win;
    __shared__ double s_pb[5];

    int tid = threadIdx.x;
    bool pre_ok = (meta[0] != 0);
    int csel = meta[1];
    int ln = 0;

    if (pre_ok) {
        int rlim = csel < RMAX ? csel : RMAX;
        int nwords = rlim * MASKW;
        for (int t = tid; t < nwords; t += BLK) smask[t] = gmask[t];
        __syncthreads();
        // single-wave greedy scan: lanes 0..15 own 64-rank alive words
        if (tid < 64) {
            int lane = tid;
            ull alive = 0ull;
            if (lane < MASKW) {
                int lo = lane << 6;
                int n = rlim - lo;
                if (n >= 64) alive = ~0ull;
                else if (n > 0) alive = (1ull << n) - 1ull;
            }
            int lnl = 0;
            while (lnl < MAX_OUT) {
                ull bal = __ballot(alive != 0ull);
                if (bal == 0ull) break;                       // exhausted -> fallback
                int wl = __ffsll(bal) - 1;                    // lowest nonzero word
                int myb = alive ? (__ffsll(alive) - 1) : 0;
                int bit = __shfl(myb, wl, 64);
                int p = (wl << 6) + bit;                      // pick = first alive rank
                if (lane == 0) s_kept[lnl] = p;               // store RANK
                lnl++;
                ull rw = (lane < MASKW) ? smask[p * MASKW + lane] : 0ull;
                alive &= ~rw;                                 // row-AND (self-bit in row)
            }
            if (lane == 0) s_ln = lnl;
        }
        __syncthreads();
        ln = s_ln;
    }

    bool need = (!pre_ok) || (ln < MAX_OUT);                  // uniform
    if (!need) {
        if (tid < MAX_OUT) write_row(reg, anc, lnd, tid, gidx[s_kept[tid]], out);
        return;
    }

    // ---- inline exact fallback: literal greedy over all N (round-10 validated) ----
    for (int i = tid; i < N_ANCHORS; i += BLK) {
        float sc = cls[i].y;
        sbuf[i] = ((double)sc > 0.4) ? sc : 0.0f;
    }
    __syncthreads();
    ln = 0;
    for (int oi = 0; oi < MAX_OUT; ++oi) {
        ull k = 0;
        for (int i = tid; i < N_ANCHORS; i += BLK) {
            ull kk = ((ull)__float_as_uint(sbuf[i]) << 32)
                   | (ull)(0xFFFFFFFFu - (unsigned int)i);
            if (kk > k) k = kk;
        }
        k = wmax(k);
        if ((tid & 63) == 0) warr[tid >> 6] = k;
        __syncthreads();
        if (tid < 64) {
            ull v = (tid < NW) ? warr[tid] : 0ull;
            v = wmax(v);
            if (tid == 0) s_win = v;
        }
        __syncthreads();
        ull win = s_win;
        if ((win >> 32) == 0u) break;
        int pidx = (int)(0xFFFFFFFFu - (unsigned int)win);
        if (tid == 0) {
            double b[4];
            decode_box_d(reg, anc, pidx, b);
            s_pb[0] = b[0]; s_pb[1] = b[1]; s_pb[2] = b[2]; s_pb[3] = b[3];
            s_pb[4] = (b[2] - b[0]) * (b[3] - b[1]);
            s_kept[oi] = pidx;                                // store IDX (fallback)
        }
        __syncthreads();
        double p0 = s_pb[0], p1 = s_pb[1], p2 = s_pb[2], p3 = s_pb[3], pa = s_pb[4];
        for (int i = tid; i < N_ANCHORS; i += BLK) {
            float v = sbuf[i];
            if (v != 0.0f) {
                double b[4];
                decode_box_d(reg, anc, i, b);
                double ih = fmin(b[2], p2) - fmax(b[0], p0); ih = fmax(ih, 0.0);
                double iw = fmin(b[3], p3) - fmax(b[1], p1); iw = fmax(iw, 0.0);
                double inter = ih * iw;
                double aa = (b[2] - b[0]) * (b[3] - b[1]);
                double den = aa + pa; den = den - inter; den = den + 1e-12;
                if (inter / den > 0.4) sbuf[i] = 0.0f;  // kills the pick too
            }
        }
        __syncthreads();
        ln = oi + 1;
    }
    __syncthreads();
    if (tid < MAX_OUT)
        write_row(reg, anc, lnd, tid, (tid < ln) ? s_kept[tid] : -1, out);
}

extern "C" void kernel_launch(void* const* d_in, const int* in_sizes, int n_in,
                              void* d_out, int out_size, void* d_ws, size_t ws_size,
                              hipStream_t stream) {
    const float2* cls = (const float2*)d_in[0];    // (N,2) f32
    const float4* reg = (const float4*)d_in[1];    // (N,4) f32
    const float*  lnd = (const float*)d_in[2];     // (N,10) f32
    const float4* anc = (const float4*)d_in[3];    // (N,4) f32

    uint8_t* w = (uint8_t*)d_ws;
    int*    segcnt  = (int*)w;                  //      0: 672 B
    int*    meta    = (int*)(w + 768);          //    768: {ok, csel}
    ull*    segkeys = (ull*)(w + 1024);         //   1024: 168*32*8 = 43008 B
    // main-path scratch unions with fallback-only sbuf (total ws use: 732160 B, unchanged)
    int*    gidx    = (int*)(w + 44032);        //  44032: 1024*4  = 4096 B
    float4* gbox    = (float4*)(w + 48128);     //  48128: 1024*16 = 16384 B
    ull*    gmask   = (ull*)(w + 64512);        //  64512: 1024*16*8 = 131072 B
    float*  sbuf    = (float*)(w + 44032);      //  44032: N*4 B (fallback only, aliases above)

    k_seg <<<GRID, BLK, 0, stream>>>(cls, segcnt, segkeys);
    k_rank<<<RGRID, RBLK, 0, stream>>>(reg, anc, segcnt, segkeys, meta, gidx, gbox);
    k_mask<<<RMAX / MROWS, MBLK, 0, stream>>>(meta, gbox, gmask);
    k_pick<<<1, BLK, 0, stream>>>(cls, reg, anc, lnd, meta, gidx, gmask, sbuf,
                                  (float*)d_out);
}

// Round 3
// 116.151 us; speedup vs baseline: 1.5297x; 1.2924x over previous
//
#include <hip/hip_runtime.h>
#include <stdint.h>

// Match numpy semantics: no FMA contraction anywhere in decision-critical math.
#pragma clang fp contract(off)

#define N_ANCHORS 172032  // compile-time problem constant
#define MAX_OUT 200
#define BLK 1024
#define GRID 168          // GRID*BLK == N_ANCHORS exactly
#define NW (BLK / 64)
#define SEG 32            // per-block segment capacity (lambda~9.6, P(>32)~1e-9; guarded)
#define NKEY (GRID * SEG) // 5376 — compact-key capacity
#define RMAX 1024         // suppression-matrix rank capacity; rank_200 < 900 (round-5
                          // evidence) so picks live in ranks [0,1024). Guarded by ln<200
                          // fallback: if the 200th pick would need rank>=RMAX the scan
                          // exhausts alive and we fall back to the exact path.
#define MASKW (RMAX / 64) // 16 ull words per row
#define MBLK 256          // k_mask block size
#define MROWS 16          // rows per k_mask block
#define RCAND 64          // candidates ranked per k_rank block (emitted by wave 0)
#define RGRID (NKEY / RCAND) // 84 rank blocks (only ~csel/64 ~ 26 stay active)
#define RBLK 512          // k_rank block size: 8 waves split the j-range (latency hiding)
#define RW (RBLK / 64)    // 8 waves
#define VT 2.35f          // fixed prefix threshold: scores ~ N(0,1) =>
                          // csel ~ 1615 +/- 40; rank_200 < 900 (round-5 evidence).
                          // Inline exact fallback guards all.

typedef unsigned long long ull;
static_assert(GRID * BLK == N_ANCHORS, "grid covers anchors exactly");
static_assert(RMAX % 64 == 0, "mask words");
static_assert(RGRID * RCAND == NKEY, "rank grid covers key capacity");
static_assert(GRID <= 192, "prefix scan uses 3 waves");

// f64 decode: f32 inputs upcast to f64, reference op order. Returns (y1,x1,y2,x2).
__device__ __forceinline__ void decode_box_d(const float4* __restrict__ reg,
                                             const float4* __restrict__ anc, int i,
                                             double b[4]) {
#pragma clang fp contract(off)
    float4 r = reg[i];
    float4 a = anc[i];
    double dx = (double)r.x * 0.1;
    double dy = (double)r.y * 0.1;
    double dw = (double)r.z * 0.2;
    double dh = (double)r.w * 0.2;
    double xa = (double)a.x, ya = (double)a.y, wa = (double)a.z, ha = (double)a.w;
    double xc = dx * wa; xc = xc + xa;     // dx*w_a + x_a
    double yc = dy * ha; yc = yc + ya;     // dy*h_a + y_a
    double w = exp(dw) * wa;
    double h = exp(dh) * ha;
    double h2 = h * 0.5, w2 = w * 0.5;
    b[0] = yc - h2; b[1] = xc - w2; b[2] = yc + h2; b[3] = xc + w2;
}

// Gather + f64 decode one output row (boxes + landmarks), write f32.
__device__ __forceinline__ void write_row(const float4* __restrict__ reg,
                                          const float4* __restrict__ anc,
                                          const float* __restrict__ lnd,
                                          int q, int idx, float* __restrict__ out) {
#pragma clang fp contract(off)
    float b[4] = {0.f, 0.f, 0.f, 0.f};
    float l10[10] = {0.f, 0.f, 0.f, 0.f, 0.f, 0.f, 0.f, 0.f, 0.f, 0.f};
    if (idx >= 0) {
        double bb[4];
        decode_box_d(reg, anc, idx, bb);
        b[0] = (float)bb[0]; b[1] = (float)bb[1]; b[2] = (float)bb[2]; b[3] = (float)bb[3];
        float4 a = anc[idx];
        double xa = (double)a.x, ya = (double)a.y, wa = (double)a.z, ha = (double)a.w;
        for (int j = 0; j < 5; ++j) {
            double lx = (double)lnd[idx * 10 + 2 * j]     * 0.1;
            double ly = (double)lnd[idx * 10 + 2 * j + 1] * 0.1;
            lx = lx * wa; lx = lx + xa;
            ly = ly * ha; ly = ly + ya;
            l10[2 * j] = (float)lx; l10[2 * j + 1] = (float)ly;
        }
    }
    for (int c = 0; c < 4; ++c)  out[q * 4 + c] = b[c];
    for (int c = 0; c < 10; ++c) out[MAX_OUT * 4 + q * 10 + c] = l10[c];
}

__device__ __forceinline__ ull wmax(ull k) {
    for (int d = 32; d > 0; d >>= 1) {
        ull o = __shfl_down(k, d, 64);
        if (o > k) k = o;
    }
    return k;
}

// uniform-lane 64-bit readlane (SGPR broadcast path — no ds_bpermute latency)
__device__ __forceinline__ ull readlane64(ull v, int l) {
    unsigned lo = (unsigned)__builtin_amdgcn_readlane((int)(unsigned)(v & 0xffffffffull), l);
    unsigned hi = (unsigned)__builtin_amdgcn_readlane((int)(unsigned)(v >> 32), l);
    return ((ull)hi << 32) | (ull)lo;
}

// f64 IoU > 0.4 test, reference op order (validated in prior rounds).
__device__ __forceinline__ bool iou_gt_f4(float4 a, float4 p) {
#pragma clang fp contract(off)
    double y1 = (double)a.x, x1 = (double)a.y, y2 = (double)a.z, x2 = (double)a.w;
    double p0 = (double)p.x, p1 = (double)p.y, p2 = (double)p.z, p3 = (double)p.w;
    double ih = fmin(y2, p2) - fmax(y1, p0); ih = fmax(ih, 0.0);
    double iw = fmin(x2, p3) - fmax(x1, p1); iw = fmax(iw, 0.0);
    double inter = ih * iw;
    double aj = (y2 - y1) * (x2 - x1);
    double ap = (p2 - p0) * (p3 - p1);
    double den = aj + ap; den = den - inter; den = den + 1e-12;
    return (inter / den) > 0.4;
}

// ---------- kernel 1: segment compaction (no atomics, no memset needed) ----------
__global__ void __launch_bounds__(BLK) k_seg(const float2* __restrict__ cls,
                                             int* __restrict__ segcnt,
                                             ull* __restrict__ segkeys) {
    __shared__ int wcnt[NW];
    int tid = threadIdx.x, bid = blockIdx.x;
    int i = bid * BLK + tid;
    float sc = cls[i].y;                   // score = cls[:,1]
    bool c = (sc > VT);
    ull key = 0ull;
    if (c) key = ((ull)__float_as_uint(sc) << 32)
               | (ull)(0xFFFFFFFFu - (unsigned int)i);
    ull m = __ballot(c);
    int wid = tid >> 6, lane = tid & 63;
    if (lane == 0) wcnt[wid] = __popcll(m);
    __syncthreads();
    if (tid == 0) {
        int s = 0;
        for (int w = 0; w < NW; ++w) { int t = wcnt[w]; wcnt[w] = s; s += t; }
        segcnt[bid] = s;                   // unconditional (overflow detected downstream)
    }
    __syncthreads();
    if (c) {
        int pos = wcnt[wid] + __popcll(m & ((1ull << lane) - 1ull));
        if (pos < SEG) segkeys[bid * SEG + pos] = key;
    }
}

// emit one ranked candidate: idx + decoded box in rank order
__device__ __forceinline__ void rank_emit(const float4* __restrict__ reg,
                                          const float4* __restrict__ anc,
                                          int rank, ull key,
                                          int* __restrict__ gidx,
                                          float4* __restrict__ gbox) {
    int idx = (int)(0xFFFFFFFFu - (unsigned int)key);
    gidx[rank] = idx;
    double b[4];
    decode_box_d(reg, anc, idx, b);
    gbox[rank] = make_float4((float)b[0], (float)b[1], (float)b[2], (float)b[3]);
}

// ---------- kernel 2: PARALLEL rank-counting sort (84 blocks x 8 waves) ----------
// Each block: (a) 3-wave shfl_up prefix scan over the 168 segment counts (replaces
// the 17us serial tid==0 prefix), (b) stage dense keys to LDS, (c) 8 waves each
// count partial ranks of this block's 64 candidates over 1/8th of the j-range
// (latency hidden across waves), (d) wave 0 sums partials and emits.
// rank = #keys strictly greater (keys unique) => value-based, block order irrelevant.
__global__ void __launch_bounds__(RBLK) k_rank(const float4* __restrict__ reg,
                                               const float4* __restrict__ anc,
                                               const int* __restrict__ segcnt,
                                               const ull* __restrict__ segkeys,
                                               int* __restrict__ meta,
                                               int* __restrict__ gidx,
                                               float4* __restrict__ gbox) {
    __shared__ ull skeys[NKEY];            // 43 KB
    __shared__ int scnt[GRID], spre[GRID];
    __shared__ int wsum[4];
    __shared__ ull wovf[4];
    __shared__ int spart[RBLK];            // per-wave partial ranks
    __shared__ int s_ok, s_csel;
    int tid = threadIdx.x, wid = tid >> 6, lane = tid & 63;

    // (a) parallel prefix over segment counts (GRID=168 -> waves 0..2)
    int v = 0; bool ovf = false;
    if (tid < GRID) { v = segcnt[tid]; scnt[tid] = v; ovf = (v > SEG); }
    int x = v;
    for (int d = 1; d < 64; d <<= 1) {
        int o = __shfl_up(x, d, 64);
        if (lane >= d) x += o;
    }
    ull om = __ballot(ovf);
    if (wid < 3 && lane == 63) { wsum[wid] = x; wovf[wid] = om; }
    __syncthreads();
    if (tid == 0) {
        int total = wsum[0] + wsum[1] + wsum[2];
        s_csel = total;
        s_ok = ((wovf[0] | wovf[1] | wovf[2]) == 0ull) ? 1 : 0;
        if (blockIdx.x == 0) { meta[0] = s_ok; meta[1] = total; }
    }
    __syncthreads();
    if (tid < GRID)
        spre[tid] = (x - v) + (wid >= 1 ? wsum[0] : 0) + (wid >= 2 ? wsum[1] : 0);
    bool okl = (s_ok != 0);
    int csel = s_csel;
    int cbase = blockIdx.x * RCAND;
    __syncthreads();                       // spre visible to all
    if (!okl) return;                      // uniform -> exact fallback in k_pick
    if (cbase >= csel) return;             // inactive tail blocks exit (uniform)

    // (b) stage dense keys (predicated scatter from padded segkeys)
    for (int t = tid; t < GRID * SEG; t += RBLK) {
        int s = t >> 5, k = t & (SEG - 1);
        if (k < scnt[s]) skeys[spre[s] + k] = segkeys[t];
    }
    __syncthreads();

    // (c) 8-wave partial rank counting (broadcast LDS reads, unroll 8)
    int per = (csel + RW - 1) / RW;
    int jb = wid * per;
    int je = jb + per; if (je > csel) je = csel;
    int c = cbase + lane;
    ull kc = (c < csel) ? skeys[c] : 0ull;
    int rk = 0;
#pragma unroll 8
    for (int j = jb; j < je; ++j)
        rk += (skeys[j] > kc) ? 1 : 0;
    spart[wid * 64 + lane] = rk;
    __syncthreads();

    // (d) wave 0: combine partials, emit rank-ordered idx + decoded box
    if (tid < RCAND) {
        int cc = cbase + tid;
        if (cc < csel) {
            int r = 0;
#pragma unroll
            for (int w = 0; w < RW; ++w) r += spart[w * 64 + tid];
            if (r < RMAX) rank_emit(reg, anc, r, skeys[cc], gidx, gbox);
        }
    }
}

// ---------- kernel 3: parallel pairwise suppression bitmatrix (64 CUs) ----------
// gmask[r][w] bit e set <=> iou(box[w*64+e], box[r]) > 0.4 (f64, reference op order).
// Diagonal bit is naturally set (iou(b,b)~1) => pick removes itself, matching the
// reference's self-suppression semantics (incl. degenerate zero-area repeat picks).
__global__ void __launch_bounds__(MBLK) k_mask(const int* __restrict__ meta,
                                               const float4* __restrict__ gbox,
                                               ull* __restrict__ gmask) {
    __shared__ float4 cbox[RMAX];          // 16 KB
    if (meta[0] == 0) return;              // uniform (before any barrier)
    int csel = meta[1];
    int rlim = csel < RMAX ? csel : RMAX;
    int tid = threadIdx.x;
    for (int t = tid; t < RMAX; t += MBLK) cbox[t] = gbox[t];  // >=rlim slots unused
    __syncthreads();
    int row  = blockIdx.x * MROWS + (tid & (MROWS - 1)); // 16-lane groups share a word
    int word = tid >> 4;                                  // => broadcast LDS col reads
    if (row >= rlim) return;
    float4 br = cbox[row];
    ull bits = 0ull;
    int cbase = word << 6;
#pragma unroll 4
    for (int e = 0; e < 64; ++e) {
        int c = cbase + e;
        if (c < rlim && iou_gt_f4(cbox[c], br)) bits |= (1ull << e);
    }
    gmask[row * MASKW + word] = bits;
}

// ---------- kernel 4: serial bit-scan greedy + output (+inline exact fallback) ----------
__global__ void __launch_bounds__(BLK) k_pick(const float2* __restrict__ cls,
                                              const float4* __restrict__ reg,
                                              const float4* __restrict__ anc,
                                              const float* __restrict__ lnd,
                                              const int* __restrict__ meta,
                                              const int* __restrict__ gidx,
                                              const ull* __restrict__ gmask,
                                              float* __restrict__ sbuf,
                                              float* __restrict__ out) {
    __shared__ __align__(16) ull smask[RMAX * MASKW]; // 128 KB (160 KiB/WG available)
    __shared__ int s_kept[MAX_OUT];
    __shared__ int s_ln;
    __shared__ ull warr[NW];               // fallback
    __shared__ ull s_win;
    __shared__ double s_pb[5];

    int tid = threadIdx.x;
    bool pre_ok = (meta[0] != 0);
    int csel = meta[1];
    int ln = 0;

    if (pre_ok) {
        int rlim = csel < RMAX ? csel : RMAX;
        // vectorized 16B copy: rlim*16 words = rlim*8 float4s
        int nv4 = rlim * (MASKW / 2);
        const float4* gm4 = (const float4*)gmask;
        float4* sm4 = (float4*)smask;
        for (int t = tid; t < nv4; t += BLK) sm4[t] = gm4[t];
        __syncthreads();
        // single-wave greedy scan: lanes 0..15 own 64-rank alive words.
        // per-pick critical path: ballot -> s_ff1 -> readlane64 -> ds_read row -> AND
        if (tid < 64) {
            int lane = tid;
            ull alive = 0ull;
            if (lane < MASKW) {
                int lo = lane << 6;
                int n = rlim - lo;
                if (n >= 64) alive = ~0ull;
                else if (n > 0) alive = (1ull << n) - 1ull;
            }
            int lnl = 0;
            while (lnl < MAX_OUT) {
                ull bal = __ballot(alive != 0ull);
                if (bal == 0ull) break;                       // exhausted -> fallback
                int wl = __ffsll(bal) - 1;                    // lowest nonzero word
                ull aw = readlane64(alive, wl);               // SGPR broadcast (no LDS)
                int bit = __ffsll(aw) - 1;
                int p = (wl << 6) + bit;                      // pick = first alive rank
                if (lane == 0) s_kept[lnl] = p;               // store RANK
                lnl++;
                ull rw = (lane < MASKW) ? smask[p * MASKW + lane] : 0ull;
                alive &= ~rw;                                 // row-AND (self-bit in row)
            }
            if (lane == 0) s_ln = lnl;
        }
        __syncthreads();
        ln = s_ln;
    }

    bool need = (!pre_ok) || (ln < MAX_OUT);                  // uniform
    if (!need) {
        if (tid < MAX_OUT) write_row(reg, anc, lnd, tid, gidx[s_kept[tid]], out);
        return;
    }

    // ---- inline exact fallback: literal greedy over all N (round-10 validated) ----
    for (int i = tid; i < N_ANCHORS; i += BLK) {
        float sc = cls[i].y;
        sbuf[i] = ((double)sc > 0.4) ? sc : 0.0f;
    }
    __syncthreads();
    ln = 0;
    for (int oi = 0; oi < MAX_OUT; ++oi) {
        ull k = 0;
        for (int i = tid; i < N_ANCHORS; i += BLK) {
            ull kk = ((ull)__float_as_uint(sbuf[i]) << 32)
                   | (ull)(0xFFFFFFFFu - (unsigned int)i);
            if (kk > k) k = kk;
        }
        k = wmax(k);
        if ((tid & 63) == 0) warr[tid >> 6] = k;
        __syncthreads();
        if (tid < 64) {
            ull v = (tid < NW) ? warr[tid] : 0ull;
            v = wmax(v);
            if (tid == 0) s_win = v;
        }
        __syncthreads();
        ull win = s_win;
        if ((win >> 32) == 0u) break;
        int pidx = (int)(0xFFFFFFFFu - (unsigned int)win);
        if (tid == 0) {
            double b[4];
            decode_box_d(reg, anc, pidx, b);
            s_pb[0] = b[0]; s_pb[1] = b[1]; s_pb[2] = b[2]; s_pb[3] = b[3];
            s_pb[4] = (b[2] - b[0]) * (b[3] - b[1]);
            s_kept[oi] = pidx;                                // store IDX (fallback)
        }
        __syncthreads();
        double p0 = s_pb[0], p1 = s_pb[1], p2 = s_pb[2], p3 = s_pb[3], pa = s_pb[4];
        for (int i = tid; i < N_ANCHORS; i += BLK) {
            float v = sbuf[i];
            if (v != 0.0f) {
                double b[4];
                decode_box_d(reg, anc, i, b);
                double ih = fmin(b[2], p2) - fmax(b[0], p0); ih = fmax(ih, 0.0);
                double iw = fmin(b[3], p3) - fmax(b[1], p1); iw = fmax(iw, 0.0);
                double inter = ih * iw;
                double aa = (b[2] - b[0]) * (b[3] - b[1]);
                double den = aa + pa; den = den - inter; den = den + 1e-12;
                if (inter / den > 0.4) sbuf[i] = 0.0f;  // kills the pick too
            }
        }
        __syncthreads();
        ln = oi + 1;
    }
    __syncthreads();
    if (tid < MAX_OUT)
        write_row(reg, anc, lnd, tid, (tid < ln) ? s_kept[tid] : -1, out);
}

extern "C" void kernel_launch(void* const* d_in, const int* in_sizes, int n_in,
                              void* d_out, int out_size, void* d_ws, size_t ws_size,
                              hipStream_t stream) {
    const float2* cls = (const float2*)d_in[0];    // (N,2) f32
    const float4* reg = (const float4*)d_in[1];    // (N,4) f32
    const float*  lnd = (const float*)d_in[2];     // (N,10) f32
    const float4* anc = (const float4*)d_in[3];    // (N,4) f32

    uint8_t* w = (uint8_t*)d_ws;
    int*    segcnt  = (int*)w;                  //      0: 672 B
    int*    meta    = (int*)(w + 768);          //    768: {ok, csel}
    ull*    segkeys = (ull*)(w + 1024);         //   1024: 168*32*8 = 43008 B
    // main-path scratch unions with fallback-only sbuf (total ws use: 732160 B, unchanged)
    int*    gidx    = (int*)(w + 44032);        //  44032: 1024*4  = 4096 B
    float4* gbox    = (float4*)(w + 48128);     //  48128: 1024*16 = 16384 B
    ull*    gmask   = (ull*)(w + 64512);        //  64512: 1024*16*8 = 131072 B (16B-aligned)
    float*  sbuf    = (float*)(w + 44032);      //  44032: N*4 B (fallback only, aliases above)

    k_seg <<<GRID, BLK, 0, stream>>>(cls, segcnt, segkeys);
    k_rank<<<RGRID, RBLK, 0, stream>>>(reg, anc, segcnt, segkeys, meta, gidx, gbox);
    k_mask<<<RMAX / MROWS, MBLK, 0, stream>>>(meta, gbox, gmask);
    k_pick<<<1, BLK, 0, stream>>>(cls, reg, anc, lnd, meta, gidx, gmask, sbuf,
                                  (float*)d_out);
}